// Round 1
// baseline (112.721 us; speedup 1.0000x reference)
//
#include <hip/hip_runtime.h>
#include <math.h>

#define B_ 16
#define R_ 4
#define S_ 4
#define T_ 14
#define F_ 2048

struct cplx { float re, im; };

__device__ __forceinline__ cplx cmul(cplx a, cplx b) {
    return {a.re*b.re - a.im*b.im, a.re*b.im + a.im*b.re};
}
// conj(a) * b
__device__ __forceinline__ cplx cmulc(cplx a, cplx b) {
    return {a.re*b.re + a.im*b.im, a.re*b.im - a.im*b.re};
}
__device__ __forceinline__ cplx cadd(cplx a, cplx b) { return {a.re+b.re, a.im+b.im}; }
__device__ __forceinline__ cplx csub(cplx a, cplx b) { return {a.re-b.re, a.im-b.im}; }
__device__ __forceinline__ cplx cscale(cplx a, float s) { return {a.re*s, a.im*s}; }
__device__ __forceinline__ cplx conjc(cplx a) { return {a.re, -a.im}; }

__global__ __launch_bounds__(256) void sic_lmmse_kernel(
    const float* __restrict__ y_re, const float* __restrict__ y_im,
    const float* __restrict__ h_re, const float* __restrict__ h_im,
    const int* __restrict__ mask, const float* __restrict__ nv,
    float* __restrict__ out)
{
    constexpr int TF  = T_ * F_;
    constexpr int N   = B_ * TF;          // one thread per (b,t,f)
    constexpr int BST = B_ * S_ * TF;     // size of one output component plane

    int idx = blockIdx.x * 256 + threadIdx.x;
    if (idx >= N) return;

    int f  = idx % F_;
    int bt = idx / F_;
    int t  = bt % T_;
    int b  = bt / T_;

    float no = nv[0];
    float m  = (float)mask[t * F_ + f];

    // ---- accumulate Hermitian gram (lower triangle) and z = H^H y ----
    cplx g[4][4];
    cplx z[4];
    #pragma unroll
    for (int i = 0; i < 4; i++) {
        z[i] = {0.f, 0.f};
        #pragma unroll
        for (int j = 0; j <= i; j++) g[i][j] = {0.f, 0.f};
    }

    #pragma unroll
    for (int r = 0; r < 4; r++) {
        int ybase = ((b * R_ + r) * T_ + t) * F_ + f;
        cplx yr = { y_re[ybase], y_im[ybase] };
        cplx hr[4];
        #pragma unroll
        for (int s = 0; s < 4; s++) {
            int hbase = (((b * R_ + r) * S_ + s) * T_ + t) * F_ + f;
            hr[s] = { h_re[hbase], h_im[hbase] };
        }
        #pragma unroll
        for (int s = 0; s < 4; s++) {
            z[s] = cadd(z[s], cmulc(hr[s], yr));          // conj(h[r][s]) * y[r]
            #pragma unroll
            for (int u = 0; u <= s; u++)
                g[s][u] = cadd(g[s][u], cmulc(hr[s], hr[u]));  // conj(h[r][s]) h[r][u]
        }
    }

    // ---- Cholesky of A = gram + no*I  (lower triangle only) ----
    cplx Lm[4][4];
    float dinv[4];
    #pragma unroll
    for (int i = 0; i < 4; i++) {
        #pragma unroll
        for (int j = 0; j < i; j++) {
            cplx s = g[i][j];
            #pragma unroll
            for (int p = 0; p < j; p++)
                s = csub(s, cmul(Lm[i][p], conjc(Lm[j][p])));
            Lm[i][j] = cscale(s, dinv[j]);
        }
        float dd = g[i][i].re + no;
        #pragma unroll
        for (int p = 0; p < i; p++)
            dd -= Lm[i][p].re * Lm[i][p].re + Lm[i][p].im * Lm[i][p].im;
        float ld = sqrtf(dd);
        dinv[i] = 1.0f / ld;
        Lm[i][i] = { ld, 0.f };
    }

    // ---- M = inv(L), lower triangular ----
    cplx M[4][4];
    #pragma unroll
    for (int i = 0; i < 4; i++) {
        #pragma unroll
        for (int j = 0; j < i; j++) {
            cplx s = {0.f, 0.f};
            #pragma unroll
            for (int p = j; p < i; p++)
                s = cadd(s, cmul(Lm[i][p], M[p][j]));
            M[i][j] = cscale(s, -dinv[i]);
        }
        M[i][i] = { dinv[i], 0.f };
    }

    // ---- W = inv(A) = M^H M, lower triangle ----
    cplx W[4][4];
    #pragma unroll
    for (int i = 0; i < 4; i++) {
        #pragma unroll
        for (int j = 0; j <= i; j++) {
            cplx s = {0.f, 0.f};
            #pragma unroll
            for (int p = i; p < 4; p++)
                s = cadd(s, cmul(conjc(M[p][i]), M[p][j]));
            W[i][j] = s;
        }
    }

    // ---- SIC loop: at step k, W = inv(gram[k:,k:] + no*I), zc = z[k:] ----
    cplx zc[4];
    #pragma unroll
    for (int j = 0; j < 4; j++) zc[j] = z[j];

    #pragma unroll
    for (int k = 0; k < 4; k++) {
        const int n = 4 - k;
        float e = W[0][0].re;                 // Ainv[k,k], real > 0
        cplx xz = cscale(zc[0], e);
        #pragma unroll
        for (int j = 1; j < 4; j++) {
            if (j < n) xz = cadd(xz, cmul(conjc(W[j][0]), zc[j]));  // W[0][j] = conj(W[j][0])
        }
        float d    = 1.0f - no * e;           // (Ainv gram0)_kk = 1 - no*Ainv_kk
        float drcp = 1.0f / d;
        cplx  xk   = cscale(xz, drcp);
        float ne   = no * e * drcp;           // (1-d)/d

        int obase = ((b * S_ + k) * T_ + t) * F_ + f;
        out[obase]            = xk.re * m;    // real(x_hat)
        out[BST + obase]      = xk.im * m;    // imag(x_hat)
        out[2 * BST + obase]  = ne * m;       // no_eff

        if (k < 3) {
            float einv = 1.0f / e;
            // z recurrence: z'[j] = z[j+1] - gram[k+j+1, k] * xk
            #pragma unroll
            for (int j = 1; j < 4; j++) {
                if (j < n) zc[j - 1] = csub(zc[j], cmul(g[k + j][k], xk));
            }
            // inverse downdate: inv(C) = G - f f^H / e
            cplx W2[3][3];
            #pragma unroll
            for (int i = 1; i < 4; i++) {
                #pragma unroll
                for (int j = 1; j <= i; j++) {
                    if (i < n)
                        W2[i - 1][j - 1] =
                            csub(W[i][j], cscale(cmul(W[i][0], conjc(W[j][0])), einv));
                }
            }
            #pragma unroll
            for (int i = 0; i < 3; i++) {
                #pragma unroll
                for (int j = 0; j <= i; j++) {
                    if (i < n - 1) W[i][j] = W2[i][j];
                }
            }
        }
    }
}

extern "C" void kernel_launch(void* const* d_in, const int* in_sizes, int n_in,
                              void* d_out, int out_size, void* d_ws, size_t ws_size,
                              hipStream_t stream) {
    const float* y_re = (const float*)d_in[0];
    const float* y_im = (const float*)d_in[1];
    const float* h_re = (const float*)d_in[2];
    const float* h_im = (const float*)d_in[3];
    const int*   mask = (const int*)  d_in[4];
    const float* nv   = (const float*)d_in[5];
    float* out = (float*)d_out;

    constexpr int N = B_ * T_ * F_;          // 458,752 = 1792 * 256
    int threads = 256;
    int blocks  = (N + threads - 1) / threads;
    hipLaunchKernelGGL(sic_lmmse_kernel, dim3(blocks), dim3(threads), 0, stream,
                       y_re, y_im, h_re, h_im, mask, nv, out);
}

// Round 2
// 111.728 us; speedup vs baseline: 1.0089x; 1.0089x over previous
//
#include <hip/hip_runtime.h>

#define B_ 16
#define R_ 4
#define S_ 4
#define T_ 14
#define F_ 2048
constexpr int P_ = F_ / 2;   // vector-of-2 elements along f

typedef float vf __attribute__((ext_vector_type(2)));

struct cplx { vf re, im; };

__device__ __forceinline__ vf vsp(float s){ vf r; r.x = s; r.y = s; return r; }
__device__ __forceinline__ vf vrcp(vf x){ vf r; r.x = __builtin_amdgcn_rcpf(x.x); r.y = __builtin_amdgcn_rcpf(x.y); return r; }
__device__ __forceinline__ vf vrsq(vf x){ vf r; r.x = __builtin_amdgcn_rsqf(x.x); r.y = __builtin_amdgcn_rsqf(x.y); return r; }

__device__ __forceinline__ cplx cmul(cplx a, cplx b) {
    return {a.re*b.re - a.im*b.im, a.re*b.im + a.im*b.re};
}
// conj(a) * b
__device__ __forceinline__ cplx cmulc(cplx a, cplx b) {
    return {a.re*b.re + a.im*b.im, a.re*b.im - a.im*b.re};
}
__device__ __forceinline__ cplx cadd(cplx a, cplx b){ return {a.re+b.re, a.im+b.im}; }
__device__ __forceinline__ cplx csub(cplx a, cplx b){ return {a.re-b.re, a.im-b.im}; }
__device__ __forceinline__ cplx cscale(cplx a, vf s){ return {a.re*s, a.im*s}; }
__device__ __forceinline__ cplx conjc(cplx a){ return {a.re, -a.im}; }

__global__ __launch_bounds__(256) void sic_lmmse_kernel(
    const float* __restrict__ y_re_, const float* __restrict__ y_im_,
    const float* __restrict__ h_re_, const float* __restrict__ h_im_,
    const int* __restrict__ mask, const float* __restrict__ nv,
    float* __restrict__ out_)
{
    constexpr int N    = B_ * T_ * P_;        // one thread per (b,t, f-pair)
    constexpr int BSTP = B_ * S_ * T_ * P_;   // one output plane, in vf units

    int idx = blockIdx.x * 256 + threadIdx.x; // N = 896*256 exactly
    int fv = idx % P_;
    int bt = idx / P_;
    int t  = bt % T_;
    int b  = bt / T_;

    const vf* y_re = (const vf*)y_re_;
    const vf* y_im = (const vf*)y_im_;
    const vf* h_re = (const vf*)h_re_;
    const vf* h_im = (const vf*)h_im_;
    vf*       out  = (vf*)out_;

    float no  = nv[0];
    vf    vno = vsp(no);

    int2 mi = ((const int2*)mask)[t * P_ + fv];
    vf m; m.x = (float)mi.x; m.y = (float)mi.y;

    // ---- gram (lower triangle) and z = H^H y ----
    cplx g[4][4];
    cplx z[4];
    #pragma unroll
    for (int i = 0; i < 4; i++) {
        z[i] = { vsp(0.f), vsp(0.f) };
        #pragma unroll
        for (int j = 0; j <= i; j++) g[i][j] = { vsp(0.f), vsp(0.f) };
    }

    #pragma unroll
    for (int r = 0; r < 4; r++) {
        int ybase = ((b * R_ + r) * T_ + t) * P_ + fv;
        cplx yr = { y_re[ybase], y_im[ybase] };
        cplx hr[4];
        #pragma unroll
        for (int s = 0; s < 4; s++) {
            int hbase = (((b * R_ + r) * S_ + s) * T_ + t) * P_ + fv;
            hr[s] = { h_re[hbase], h_im[hbase] };
        }
        #pragma unroll
        for (int s = 0; s < 4; s++) {
            z[s] = cadd(z[s], cmulc(hr[s], yr));
            #pragma unroll
            for (int u = 0; u <= s; u++)
                g[s][u] = cadd(g[s][u], cmulc(hr[s], hr[u]));
        }
    }

    // ---- Cholesky of A = gram + no*I; only dinv + off-diag L needed ----
    cplx Lm[4][4];          // off-diagonal entries only; diagonal never read
    vf dinv[4];
    #pragma unroll
    for (int i = 0; i < 4; i++) {
        #pragma unroll
        for (int j = 0; j < i; j++) {
            cplx s = g[i][j];
            #pragma unroll
            for (int p = 0; p < j; p++)
                s = csub(s, cmul(Lm[i][p], conjc(Lm[j][p])));
            Lm[i][j] = cscale(s, dinv[j]);
        }
        vf dd = g[i][i].re + vno;
        #pragma unroll
        for (int p = 0; p < i; p++)
            dd = dd - (Lm[i][p].re * Lm[i][p].re + Lm[i][p].im * Lm[i][p].im);
        dinv[i] = vrsq(dd);                   // 1/sqrt(dd) via v_rsq_f32
    }

    // ---- M = inv(L), lower triangular ----
    cplx M[4][4];
    #pragma unroll
    for (int i = 0; i < 4; i++) {
        #pragma unroll
        for (int j = 0; j < i; j++) {
            cplx s = { vsp(0.f), vsp(0.f) };
            #pragma unroll
            for (int p = j; p < i; p++)
                s = cadd(s, cmul(Lm[i][p], M[p][j]));
            M[i][j] = cscale(s, -dinv[i]);
        }
        M[i][i] = { dinv[i], vsp(0.f) };
    }

    // ---- W = inv(A) = M^H M, lower triangle ----
    cplx W[4][4];
    #pragma unroll
    for (int i = 0; i < 4; i++) {
        #pragma unroll
        for (int j = 0; j <= i; j++) {
            cplx s = { vsp(0.f), vsp(0.f) };
            #pragma unroll
            for (int p = i; p < 4; p++)
                s = cadd(s, cmul(conjc(M[p][i]), M[p][j]));
            W[i][j] = s;
        }
    }

    // ---- SIC loop: W = inv(gram[k:,k:] + no*I), zc = z[k:] ----
    cplx zc[4];
    #pragma unroll
    for (int j = 0; j < 4; j++) zc[j] = z[j];

    #pragma unroll
    for (int k = 0; k < 4; k++) {
        const int n = 4 - k;
        vf e = W[0][0].re;                    // Ainv[k,k], real > 0
        cplx xz = cscale(zc[0], e);
        #pragma unroll
        for (int j = 1; j < 4; j++) {
            if (j < n) xz = cadd(xz, cmul(conjc(W[j][0]), zc[j]));
        }
        vf d    = vsp(1.0f) - vno * e;        // (Ainv gram0)_kk = 1 - no*Ainv_kk
        vf drcp = vrcp(d);
        cplx xk = cscale(xz, drcp);
        vf ne   = vno * e * drcp;             // (1-d)/d

        int obase = ((b * S_ + k) * T_ + t) * P_ + fv;
        out[obase]            = xk.re * m;
        out[BSTP + obase]     = xk.im * m;
        out[2 * BSTP + obase] = ne * m;

        if (k < 3) {
            vf einv = vrcp(e);
            #pragma unroll
            for (int j = 1; j < 4; j++) {
                if (j < n) zc[j - 1] = csub(zc[j], cmul(g[k + j][k], xk));
            }
            cplx W2[3][3];
            #pragma unroll
            for (int i = 1; i < 4; i++) {
                #pragma unroll
                for (int j = 1; j <= i; j++) {
                    if (i < n)
                        W2[i - 1][j - 1] =
                            csub(W[i][j], cscale(cmul(W[i][0], conjc(W[j][0])), einv));
                }
            }
            #pragma unroll
            for (int i = 0; i < 3; i++) {
                #pragma unroll
                for (int j = 0; j <= i; j++) {
                    if (i < n - 1) W[i][j] = W2[i][j];
                }
            }
        }
    }
}

extern "C" void kernel_launch(void* const* d_in, const int* in_sizes, int n_in,
                              void* d_out, int out_size, void* d_ws, size_t ws_size,
                              hipStream_t stream) {
    const float* y_re = (const float*)d_in[0];
    const float* y_im = (const float*)d_in[1];
    const float* h_re = (const float*)d_in[2];
    const float* h_im = (const float*)d_in[3];
    const int*   mask = (const int*)  d_in[4];
    const float* nv   = (const float*)d_in[5];
    float* out = (float*)d_out;

    constexpr int N = B_ * T_ * P_;          // 229,376 = 896 * 256
    int threads = 256;
    int blocks  = N / threads;
    hipLaunchKernelGGL(sic_lmmse_kernel, dim3(blocks), dim3(threads), 0, stream,
                       y_re, y_im, h_re, h_im, mask, nv, out);
}